// Round 9
// baseline (422.465 us; speedup 1.0000x reference)
//
#include <hip/hip_runtime.h>
#include <hip/hip_bf16.h>

typedef __attribute__((ext_vector_type(8))) short s8v;
typedef __attribute__((ext_vector_type(4))) float f32x4;
using bf16 = __hip_bfloat16;

#define LN_EPS 1e-5f

__device__ __forceinline__ float bf2f(unsigned short b){ return __uint_as_float(((unsigned)b)<<16); }
__device__ __forceinline__ unsigned short f2bf(float f){ __hip_bfloat16 h = __float2bfloat16(f); return *reinterpret_cast<unsigned short*>(&h); }

// MFMA k-half permutation: stored position of true k within each 32-k block.
__device__ __forceinline__ int posk(int k){
    int q = (k >> 2) & 7;
    int s = (q < 4) ? (2*q) : (2*q - 7);
    return (k & ~31) | (s << 2) | (k & 3);
}

__device__ __forceinline__ void async16(const void* g, void* l){
    __builtin_amdgcn_global_load_lds(
        (const __attribute__((address_space(1))) unsigned int*)g,
        (__attribute__((address_space(3))) unsigned int*)l, 16, 0, 0);
}

// ---------------- fused LayerNorm -> padded+permuted bf16 A-matrix ----------------
__global__ __launch_bounds__(256) void ln_fused(const float* __restrict__ x,
        const float* __restrict__ g, const float* __restrict__ b,
        unsigned short* __restrict__ xln)
{
    int lane = threadIdx.x & 63, wv = threadIdx.x >> 6;
    long row = (long)blockIdx.x * 4 + wv;
    const float* xr = x + row * 400;
    float v[7];
    float s = 0.f, ss = 0.f;
    #pragma unroll
    for (int i = 0; i < 7; ++i) {
        int n = lane + i * 64;
        float t = (n < 400) ? xr[n] : 0.f;
        v[i] = t; s += t; ss += t * t;
    }
    #pragma unroll
    for (int o = 32; o; o >>= 1) { s += __shfl_down(s, o); ss += __shfl_down(ss, o); }
    s = __shfl(s, 0); ss = __shfl(ss, 0);
    float mu = s * 0.0025f;
    float rstd = rsqrtf(ss * 0.0025f - mu * mu + LN_EPS);
    unsigned short* orow = xln + row * 448;
    #pragma unroll
    for (int i = 0; i < 7; ++i) {
        int n = lane + i * 64;
        float t = (n < 400) ? ((v[i] - mu) * rstd * g[n] + b[n]) : 0.f;
        orow[posk(n)] = f2bf(t);
    }
}

// ---------------- weight prep: pad + posk-permute + optional hi/lo split along K ----------------
__global__ void prep_w(const float* __restrict__ src, int R0, int K0,
                       unsigned short* __restrict__ dst, int K2, int khalf)
{
    int k = blockIdx.x * 256 + threadIdx.x;
    if (k >= K2) return;
    int r = blockIdx.y;
    int ks = k, half = 0;
    if (khalf && k >= khalf) { ks = k - khalf; half = 1; }
    float v = 0.f;
    if (r < R0 && ks < K0) v = src[(long)r * K0 + ks];
    unsigned short out;
    if (!khalf) out = f2bf(v);
    else {
        float hi = bf2f(f2bf(v));
        out = half ? f2bf(v - hi) : f2bf(hi);
    }
    dst[(long)r * K2 + posk(k)] = out;
}

// ---------------- param prep ----------------
__global__ void prep_params(
    const float* __restrict__ b1, const float* __restrict__ b2,
    const float* __restrict__ c1b, const float* __restrict__ g1, const float* __restrict__ bb1,
    const float* __restrict__ m1, const float* __restrict__ v1,
    const float* __restrict__ c2b, const float* __restrict__ g2, const float* __restrict__ bb2,
    const float* __restrict__ m2, const float* __restrict__ v2,
    float* __restrict__ b1p, float* __restrict__ b2p,
    float* __restrict__ sc1, float* __restrict__ sh1,
    float* __restrict__ sc2, float* __restrict__ sh2)
{
    int t = threadIdx.x;
    if (t < 512) {
        b1p[t] = (t < 400) ? b1[t] : 0.f;
        b2p[t] = (t < 400) ? b2[t] : 0.f;
        float sc = 0.f, sh = 0.f;
        if (t < 400) { sc = g1[t] / sqrtf(v1[t] + LN_EPS); sh = (c1b[t] - m1[t]) * sc + bb1[t]; }
        sc1[t] = sc; sh1[t] = sh;
    }
    float sc = g2[t] / sqrtf(v2[t] + LN_EPS);
    sc2[t] = sc;
    sh2[t] = (c2b[t] - m2[t]) * sc + bb2[t];
}

// ---------------- LIF1: scan x[b][c][n] directly -> s[(n*64+b)][posk(c)] ----------
__global__ __launch_bounds__(128) void lif1(const float* __restrict__ x, unsigned short* __restrict__ s)
{
    __shared__ char bufc[8 * 5200];
    const int tid = threadIdx.x;
    const int lane = tid & 63, w = tid >> 6;
    const int c0 = blockIdx.x * 128, b = blockIdx.y;
    const int pc = posk(c0 + tid);
    const int r = lane >> 2;        // row within 16-row group
    const int nq = lane & 3;        // 16B chunk within 64B row-piece
    const int tg = tid >> 4, tr = tid & 15;
    const float* xb = x + (long)b * 409600;
    float v = 0.f;
    for (int q = 0; q < 5; ++q) {
        int n0 = q * 80;
        #pragma unroll
        for (int g2 = 0; g2 < 4; ++g2) {
            int g = w * 4 + g2;
            const float* srcbase = xb + (long)(c0 + g * 16 + r) * 400 + n0 + nq * 4;
            char* dstbase = bufc + g * 5200;
            #pragma unroll
            for (int sub = 0; sub < 5; ++sub)
                async16(srcbase + sub * 16, dstbase + sub * 1024);
        }
        __syncthreads();
        const float* bw = (const float*)(bufc + tg * 5200) + tr * 16;
        #pragma unroll 8
        for (int nl = 0; nl < 80; ++nl) {
            float cur = bw[(nl >> 4) * 256 + (nl & 15)];
            v += (cur - v) * 0.5f;
            bool sk = (v >= 1.0f);
            s[((long)(n0 + nl) * 64 + b) * 1024 + pc] = sk ? (unsigned short)0x3F80 : (unsigned short)0;
            if (sk) v = 0.f;
        }
        __syncthreads();
    }
}

// ---------------- LIF2: LDS-staged scan over y[(n*64+b)][o] -> s2[(n*64+b)][posk(o)] ----------
__global__ __launch_bounds__(128) void lif2(const float* __restrict__ y, unsigned short* __restrict__ s2)
{
    __shared__ float buf[40][128];
    const int tid = threadIdx.x;
    const int lane = tid & 63, w = tid >> 6;
    const int o0 = blockIdx.x * 128, b = blockIdx.y;
    const int o = o0 + tid;
    const int pco = (o < 448) ? posk(o) : 0;
    const int rsub = lane >> 5;
    const int koff = (lane & 31) << 2;
    float v = 0.f;
    for (int n0 = 0; n0 < 400; n0 += 40) {
        #pragma unroll
        for (int g = 0; g < 10; ++g) {
            int r = w * 20 + g * 2;
            const float* src = y + ((long)(n0 + r + rsub) * 64 + b) * 512 + o0 + koff;
            async16(src, &buf[r][0]);
        }
        __syncthreads();
        #pragma unroll 8
        for (int r = 0; r < 40; ++r) {
            float cur = buf[r][tid];
            v += (cur - v) * 0.5f;
            bool sk = (v >= 1.0f);
            if (o < 448)
                s2[((long)(n0 + r) * 64 + b) * 448 + pco] = sk ? (unsigned short)0x3F80 : (unsigned short)0;
            if (sk) v = 0.f;
        }
        __syncthreads();
    }
}

// ---------------- MFMA GEMM 256x256 tile: D[m][n] = sum_k A[m][k]*B[n][k] -------------------
// 512 threads = 8 waves (2m x 4n), per-wave 128x64 output (acc[8][4]). BK=64,
// double-buffered 128KB LDS, counted vmcnt(8) 2-phase pipeline (T3/T4 minimal).
// Panel-grouped 1-D dispatch: xcd=id&7 -> panel-sharers at ids p,p+8,.. (same XCD L2).
// Pb = count along the XCD-spread dim (early-return guard for non-multiple-of-8).
template<int EPI, int GMODE, int NBL>
__global__ __launch_bounds__(512) void mfma_gemm(
    const unsigned short* __restrict__ A, int ldA, long sAb,
    const unsigned short* __restrict__ B, int ldB,
    int KT, int wrapK,
    void* __restrict__ Cv,
    const float* __restrict__ p0, const float* __restrict__ p1,
    int Pb)
{
    __shared__ char LDS[2][65536];   // [buf][A 32KB | B 32KB]
    const int tid = threadIdx.x;
    const int lane = tid & 63, wid = tid >> 6;
    const int wm = wid >> 2, wn = wid & 3;
    int m0, n0, bz = 0;
    {
        int id = blockIdx.x;
        int xcd = id & 7, q = id >> 3;
        if (GMODE == 0) {
            int nb = q & ((1 << NBL) - 1);
            int rest = q >> NBL;
            int mi = rest * 8 + xcd;
            if (mi >= Pb) return;
            m0 = mi << 8; n0 = nb << 8;
        } else if (GMODE == 1) {
            int mb = q & ((1 << NBL) - 1);
            int rest = q >> NBL;
            int ni = rest * 8 + xcd;
            if (ni >= Pb) return;
            n0 = ni << 8; m0 = mb << 8;
        } else {
            int nb = q & ((1 << NBL) - 1);
            int rest = q >> NBL;
            int p = rest * 8 + xcd;
            if (p >= Pb) return;
            bz = p & 63;
            m0 = (p >> 6) << 8;
            n0 = nb << 8;
        }
    }
    const unsigned short* Ab = A + (long)bz * sAb;

    const int srow = lane >> 3;
    const int koff = (lane & 7) << 4;
    const int ssw  = (srow & 7) << 4;

    f32x4 acc[8][4];
    #pragma unroll
    for (int i = 0; i < 8; ++i)
        #pragma unroll
        for (int j = 0; j < 4; ++j)
            acc[i][j] = (f32x4){0.f, 0.f, 0.f, 0.f};

    auto stage = [&](char* dst, int kt){
        int k0 = kt << 6;
        int k0a = (wrapK && k0 >= wrapK) ? (k0 - wrapK) : k0;
        #pragma unroll
        for (int qq = 0; qq < 4; ++qq) {
            int i = (wid << 2) + qq;         // 0..31 (32 x 1KB segments)
            int row = (i << 3) + srow;       // 0..255
            const char* gA = (const char*)(Ab + (long)(m0 + row) * ldA + k0a) + (koff ^ ssw);
            async16(gA, dst + (i << 10));
            const char* gB = (const char*)(B + (long)(n0 + row) * ldB + k0) + (koff ^ ssw);
            async16(gB, dst + 32768 + (i << 10));
        }
    };

    const int r16 = lane & 15;
    const int swl = (r16 & 7) << 4;

    stage(LDS[0], 0);   // prologue: 8 loads/lane in flight
    int cur = 0;
    for (int kt = 0; kt < KT; ++kt) {
        asm volatile("" ::: "memory");
        if (kt + 1 < KT) {
            stage(LDS[cur ^ 1], kt + 1);                       // +8 (16 outstanding)
            asm volatile("s_waitcnt vmcnt(8)" ::: "memory");   // cur-tile loads landed
        } else {
            asm volatile("s_waitcnt vmcnt(0)" ::: "memory");
        }
        __builtin_amdgcn_s_barrier();
        asm volatile("" ::: "memory");
        __builtin_amdgcn_sched_barrier(0);
        const char* AsB = LDS[cur];
        const char* BsB = LDS[cur] + 32768;
        #pragma unroll
        for (int kk = 0; kk < 2; ++kk) {
            int kb = (kk << 6) + ((lane >> 4) << 4);
            s8v af[8], bv[4];
            #pragma unroll
            for (int f = 0; f < 8; ++f) {
                int rowA = (wm << 7) + (f << 4) + r16;
                af[f] = *reinterpret_cast<const s8v*>(AsB + (rowA << 7) + (kb ^ swl));
            }
            #pragma unroll
            for (int f = 0; f < 4; ++f) {
                int rowB = (wn << 6) + (f << 4) + r16;
                bv[f] = *reinterpret_cast<const s8v*>(BsB + (rowB << 7) + (kb ^ swl));
            }
            #pragma unroll
            for (int fi = 0; fi < 8; ++fi)
                #pragma unroll
                for (int fj = 0; fj < 4; ++fj)
                    acc[fi][fj] = __builtin_amdgcn_mfma_f32_16x16x32_bf16(af[fi], bv[fj], acc[fi][fj], 0, 0, 0);
        }
        asm volatile("" ::: "memory");
        __builtin_amdgcn_s_barrier();   // all waves done with LDS[cur] before restage
        cur ^= 1;
    }

    const int g4 = (lane >> 4) << 2;
    unsigned short* hC = (unsigned short*)Cv;
    float* fC = (float*)Cv;
    #pragma unroll
    for (int fi = 0; fi < 8; ++fi) {
        #pragma unroll
        for (int fj = 0; fj < 4; ++fj) {
            int col = n0 + (wn << 6) + (fj << 4) + r16;
            int row0 = m0 + (wm << 7) + (fi << 4) + g4;
            f32x4 a = acc[fi][fj];
            if (EPI == 0) {
                if (col < 448) {
                    float bias = p0[col];
                    int pc = posk(col);
                    #pragma unroll
                    for (int r = 0; r < 4; ++r)
                        hC[(long)(row0 + r) * 448 + pc] = f2bf(fmaxf(a[r] + bias, 0.f));
                }
            } else if (EPI == 1) {
                int bb = col >> 10, cc = col & 1023;
                int pc = posk(cc);
                if (row0 < 400) {
                    float4 rv = *reinterpret_cast<const float4*>(p1 + ((long)bb * 1024 + cc) * 400 + row0);
                    float ra[4] = {rv.x, rv.y, rv.z, rv.w};
                    #pragma unroll
                    for (int r = 0; r < 4; ++r) {
                        float t = a[r] + p0[row0 + r] + ra[r];
                        hC[(long)bb * 409600 + (long)(row0 + r) * 1024 + pc] = f2bf(t);
                    }
                }
            } else if (EPI == 2) {
                float sc = p0[col], sh = p1[col];
                #pragma unroll
                for (int r = 0; r < 4; ++r)
                    fC[(long)(row0 + r) * 512 + col] = a[r] * sc + sh;
            } else if (EPI == 3) {
                float sc = p0[col], sh = p1[col];
                int pc = posk(col);
                #pragma unroll
                for (int r = 0; r < 4; ++r) {
                    int row = row0 + r;
                    int nn = row >> 6, bbb = row & 63;
                    long ad = ((long)bbb * 400 + nn) * 1024 + pc;
                    hC[ad] = f2bf(bf2f(hC[ad]) + a[r] * sc + sh);
                }
            } else {
                float bias = p0[col];
                if (row0 < 400) {
                    #pragma unroll
                    for (int r = 0; r < 4; ++r)
                        hC[(long)bz * 204800 + (long)(row0 + r) * 512 + col] = f2bf(a[r] + bias);
                }
            }
        }
    }
}

// ---------------- rp GEMM + L2 normalize (xc is bf16 [b][n][o]) ----------------
__global__ __launch_bounds__(512) void rp_norm(const unsigned short* __restrict__ xc,
        const float* __restrict__ rpw, const float* __restrict__ rpb,
        float* __restrict__ out)
{
    __shared__ float wr[1600];
    __shared__ float red[8];
    int b = blockIdx.x, o = threadIdx.x;
    for (int i = o; i < 1600; i += 512) wr[i] = rpw[i];
    __syncthreads();
    const unsigned short* xb = xc + (long)b * 204800 + o;
    float a0 = rpb[0], a1 = rpb[1], a2 = rpb[2], a3 = rpb[3];
    #pragma unroll 4
    for (int n = 0; n < 400; ++n) {
        float xv = bf2f(xb[(long)n * 512]);
        a0 = fmaf(xv, wr[n], a0);
        a1 = fmaf(xv, wr[400 + n], a1);
        a2 = fmaf(xv, wr[800 + n], a2);
        a3 = fmaf(xv, wr[1200 + n], a3);
    }
    float sq = a0*a0 + a1*a1 + a2*a2 + a3*a3;
    #pragma unroll
    for (int off2 = 32; off2; off2 >>= 1) sq += __shfl_down(sq, off2);
    if ((o & 63) == 0) red[o >> 6] = sq;
    __syncthreads();
    if (o == 0) {
        float t = 0.f;
        #pragma unroll
        for (int i = 0; i < 8; ++i) t += red[i];
        red[0] = fmaxf(sqrtf(t), 1e-12f);
    }
    __syncthreads();
    float inv = 1.f / red[0];
    float4 ov = make_float4(a0*inv, a1*inv, a2*inv, a3*inv);
    *reinterpret_cast<float4*>(out + (long)b * 2048 + o * 4) = ov;
}

extern "C" void kernel_launch(void* const* d_in, const int* in_sizes, int n_in,
                              void* d_out, int out_size, void* d_ws, size_t ws_size,
                              hipStream_t stream) {
    const float* x    = (const float*)d_in[0];
    const float* ln_g = (const float*)d_in[1];
    const float* ln_b = (const float*)d_in[2];
    const float* w1   = (const float*)d_in[3];
    const float* b1   = (const float*)d_in[4];
    const float* w2   = (const float*)d_in[5];
    const float* b2   = (const float*)d_in[6];
    const float* c1w  = (const float*)d_in[7];
    const float* c1b  = (const float*)d_in[8];
    const float* bn1g = (const float*)d_in[9];
    const float* bn1b = (const float*)d_in[10];
    const float* bn1m = (const float*)d_in[11];
    const float* bn1v = (const float*)d_in[12];
    const float* c2w  = (const float*)d_in[13];
    const float* c2b  = (const float*)d_in[14];
    const float* bn2g = (const float*)d_in[15];
    const float* bn2b = (const float*)d_in[16];
    const float* bn2m = (const float*)d_in[17];
    const float* bn2v = (const float*)d_in[18];
    const float* cpw  = (const float*)d_in[19];
    const float* cpb  = (const float*)d_in[20];
    const float* rpw  = (const float*)d_in[21];
    const float* rpb  = (const float*)d_in[22];

    char* ws = (char*)d_ws;
    size_t off = 0;
    auto alloc = [&](size_t n){ size_t o = off; off += (n + 255) & ~(size_t)255; return o; };

    unsigned short* regA = (unsigned short*)(ws + alloc(58720256));
    unsigned short* regB = (unsigned short*)(ws + alloc(58720256));
    char* regC = ws + alloc(104857600);

    unsigned short* xln  = regA;
    unsigned short* x1bf = regA;
    unsigned short* h1   = regB;
    unsigned short* s    = regB;
    float* y  = (float*)regC;                                // 25600*512*4 = 52.4MB
    unsigned short* s2 = (unsigned short*)(regC + 52428800); // 25600*448*2 = 22.9MB
    unsigned short* xc = (unsigned short*)regC;              // 64*400*512*2 (after lif2 consumes y)

    unsigned short* w1p  = (unsigned short*)(ws + alloc(458752));
    unsigned short* w2p  = (unsigned short*)(ws + alloc(458752));
    unsigned short* w1c  = (unsigned short*)(ws + alloc(2097152));  // [512][2048] hi|lo
    unsigned short* w2c  = (unsigned short*)(ws + alloc(1835008));  // [1024][448]
    unsigned short* cpwp = (unsigned short*)(ws + alloc(1048576));
    float* b1p = (float*)(ws + alloc(2048));
    float* b2p = (float*)(ws + alloc(2048));
    float* sc1 = (float*)(ws + alloc(2048));
    float* sh1 = (float*)(ws + alloc(2048));
    float* sc2 = (float*)(ws + alloc(4096));
    float* sh2 = (float*)(ws + alloc(4096));

    prep_w<<<dim3(2, 512), 256, 0, stream>>>(w1, 400, 400, w1p, 448, 0);
    prep_w<<<dim3(2, 512), 256, 0, stream>>>(w2, 400, 400, w2p, 448, 0);
    prep_w<<<dim3(8, 512), 256, 0, stream>>>(c1w, 400, 1024, w1c, 2048, 1024);
    prep_w<<<dim3(2, 1024), 256, 0, stream>>>(c2w, 1024, 400, w2c, 448, 0);
    prep_w<<<dim3(4, 512), 256, 0, stream>>>(cpw, 512, 1024, cpwp, 1024, 0);
    prep_params<<<1, 1024, 0, stream>>>(b1, b2, c1b, bn1g, bn1b, bn1m, bn1v,
                                        c2b, bn2g, bn2b, bn2m, bn2v,
                                        b1p, b2p, sc1, sh1, sc2, sh2);

    // 1) LN(x) -> xln
    ln_fused<<<16384, 256, 0, stream>>>(x, ln_g, ln_b, xln);

    // 2) h1 = relu(xln @ w1p^T + b1)   [GMODE0: 256 m-panels spread over XCDs, 2 n-blocks]
    mfma_gemm<0,0,1><<<dim3(512), 512, 0, stream>>>(xln, 448, 0, w1p, 448, 7, 0, h1, b1p, nullptr, 256);

    // 3) x1bf[b][n][c] = (h1 @ w2^T)^T + b2 + x   [GMODE1: 256 n-panels (h1), 2 m-blocks]
    mfma_gemm<1,1,1><<<dim3(512), 512, 0, stream>>>(w2p, 448, 0, h1, 448, 7, 0, x1bf, b2p, x, 256);

    // 4) LIF1 (direct x scan): -> s
    lif1<<<dim3(8, 64), 128, 0, stream>>>(x, s);

    // 5) conv1+bn1 (hi/lo split, K=2048 wrap 1024)  [GMODE0: 100 m-panels, 2 n-blocks]
    mfma_gemm<2,0,1><<<dim3(208), 512, 0, stream>>>(s, 1024, 0, w1c, 2048, 32, 1024, y, sc1, sh1, 100);

    // 6) LIF2 (LDS-staged): y -> s2
    lif2<<<dim3(4, 64), 128, 0, stream>>>(y, s2);

    // 7) conv2+bn2 (K=448; RMW into x1bf)  [GMODE0: 100 m-panels, 4 n-blocks]
    mfma_gemm<3,0,2><<<dim3(416), 512, 0, stream>>>(s2, 448, 0, w2c, 448, 7, 0, x1bf, sc2, sh2, 100);

    // 8) cp: xc[b][n][o] = x1bf[b] @ cpw^T + cpb (bf16 out)  [GMODE2: 128 (b,m)-panels, 2 n-blocks]
    mfma_gemm<4,2,1><<<dim3(256), 512, 0, stream>>>(x1bf, 1024, 409600, cpwp, 1024, 16, 0, xc, cpb, nullptr, 128);

    // 9) rp + L2 normalize
    rp_norm<<<64, 512, 0, stream>>>(xc, rpw, rpb, (float*)d_out);
}

// Round 10
// 406.066 us; speedup vs baseline: 1.0404x; 1.0404x over previous
//
#include <hip/hip_runtime.h>
#include <hip/hip_bf16.h>

typedef __attribute__((ext_vector_type(8))) short s8v;
typedef __attribute__((ext_vector_type(4))) float f32x4;
using bf16 = __hip_bfloat16;

#define LN_EPS 1e-5f

__device__ __forceinline__ float bf2f(unsigned short b){ return __uint_as_float(((unsigned)b)<<16); }
__device__ __forceinline__ unsigned short f2bf(float f){ __hip_bfloat16 h = __float2bfloat16(f); return *reinterpret_cast<unsigned short*>(&h); }

// MFMA k-half permutation: stored position of true k within each 32-k block.
__device__ __forceinline__ int posk(int k){
    int q = (k >> 2) & 7;
    int s = (q < 4) ? (2*q) : (2*q - 7);
    return (k & ~31) | (s << 2) | (k & 3);
}

__device__ __forceinline__ void async16(const void* g, void* l){
    __builtin_amdgcn_global_load_lds(
        (const __attribute__((address_space(1))) unsigned int*)g,
        (__attribute__((address_space(3))) unsigned int*)l, 16, 0, 0);
}

// ---------------- fused LayerNorm -> padded+permuted bf16 A-matrix ----------------
__global__ __launch_bounds__(256) void ln_fused(const float* __restrict__ x,
        const float* __restrict__ g, const float* __restrict__ b,
        unsigned short* __restrict__ xln)
{
    int lane = threadIdx.x & 63, wv = threadIdx.x >> 6;
    long row = (long)blockIdx.x * 4 + wv;
    const float* xr = x + row * 400;
    float v[7];
    float s = 0.f, ss = 0.f;
    #pragma unroll
    for (int i = 0; i < 7; ++i) {
        int n = lane + i * 64;
        float t = (n < 400) ? xr[n] : 0.f;
        v[i] = t; s += t; ss += t * t;
    }
    #pragma unroll
    for (int o = 32; o; o >>= 1) { s += __shfl_down(s, o); ss += __shfl_down(ss, o); }
    s = __shfl(s, 0); ss = __shfl(ss, 0);
    float mu = s * 0.0025f;
    float rstd = rsqrtf(ss * 0.0025f - mu * mu + LN_EPS);
    unsigned short* orow = xln + row * 448;
    #pragma unroll
    for (int i = 0; i < 7; ++i) {
        int n = lane + i * 64;
        float t = (n < 400) ? ((v[i] - mu) * rstd * g[n] + b[n]) : 0.f;
        orow[posk(n)] = f2bf(t);
    }
}

// ---------------- weight prep: pad + posk-permute + optional hi/lo split along K ----------------
__global__ void prep_w(const float* __restrict__ src, int R0, int K0,
                       unsigned short* __restrict__ dst, int K2, int khalf)
{
    int k = blockIdx.x * 256 + threadIdx.x;
    if (k >= K2) return;
    int r = blockIdx.y;
    int ks = k, half = 0;
    if (khalf && k >= khalf) { ks = k - khalf; half = 1; }
    float v = 0.f;
    if (r < R0 && ks < K0) v = src[(long)r * K0 + ks];
    unsigned short out;
    if (!khalf) out = f2bf(v);
    else {
        float hi = bf2f(f2bf(v));
        out = half ? f2bf(v - hi) : f2bf(hi);
    }
    dst[(long)r * K2 + posk(k)] = out;
}

// ---------------- param prep ----------------
__global__ void prep_params(
    const float* __restrict__ b1, const float* __restrict__ b2,
    const float* __restrict__ c1b, const float* __restrict__ g1, const float* __restrict__ bb1,
    const float* __restrict__ m1, const float* __restrict__ v1,
    const float* __restrict__ c2b, const float* __restrict__ g2, const float* __restrict__ bb2,
    const float* __restrict__ m2, const float* __restrict__ v2,
    float* __restrict__ b1p, float* __restrict__ b2p,
    float* __restrict__ sc1, float* __restrict__ sh1,
    float* __restrict__ sc2, float* __restrict__ sh2)
{
    int t = threadIdx.x;
    if (t < 512) {
        b1p[t] = (t < 400) ? b1[t] : 0.f;
        b2p[t] = (t < 400) ? b2[t] : 0.f;
        float sc = 0.f, sh = 0.f;
        if (t < 400) { sc = g1[t] / sqrtf(v1[t] + LN_EPS); sh = (c1b[t] - m1[t]) * sc + bb1[t]; }
        sc1[t] = sc; sh1[t] = sh;
    }
    float sc = g2[t] / sqrtf(v2[t] + LN_EPS);
    sc2[t] = sc;
    sh2[t] = (c2b[t] - m2[t]) * sc + bb2[t];
}

// ---------------- LIF1: scan x[b][c][n] directly -> s[(n*64+b)][posk(c)] ----------
__global__ __launch_bounds__(128) void lif1(const float* __restrict__ x, unsigned short* __restrict__ s)
{
    __shared__ char bufc[8 * 5200];
    const int tid = threadIdx.x;
    const int lane = tid & 63, w = tid >> 6;
    const int c0 = blockIdx.x * 128, b = blockIdx.y;
    const int pc = posk(c0 + tid);
    const int r = lane >> 2;        // row within 16-row group
    const int nq = lane & 3;        // 16B chunk within 64B row-piece
    const int tg = tid >> 4, tr = tid & 15;
    const float* xb = x + (long)b * 409600;
    float v = 0.f;
    for (int q = 0; q < 5; ++q) {
        int n0 = q * 80;
        #pragma unroll
        for (int g2 = 0; g2 < 4; ++g2) {
            int g = w * 4 + g2;
            const float* srcbase = xb + (long)(c0 + g * 16 + r) * 400 + n0 + nq * 4;
            char* dstbase = bufc + g * 5200;
            #pragma unroll
            for (int sub = 0; sub < 5; ++sub)
                async16(srcbase + sub * 16, dstbase + sub * 1024);
        }
        __syncthreads();
        const float* bw = (const float*)(bufc + tg * 5200) + tr * 16;
        #pragma unroll 8
        for (int nl = 0; nl < 80; ++nl) {
            float cur = bw[(nl >> 4) * 256 + (nl & 15)];
            v += (cur - v) * 0.5f;
            bool sk = (v >= 1.0f);
            s[((long)(n0 + nl) * 64 + b) * 1024 + pc] = sk ? (unsigned short)0x3F80 : (unsigned short)0;
            if (sk) v = 0.f;
        }
        __syncthreads();
    }
}

// ---------------- LIF2: LDS-staged scan over y[(n*64+b)][o] -> s2[(n*64+b)][posk(o)] ----------
__global__ __launch_bounds__(128) void lif2(const float* __restrict__ y, unsigned short* __restrict__ s2)
{
    __shared__ float buf[40][128];
    const int tid = threadIdx.x;
    const int lane = tid & 63, w = tid >> 6;
    const int o0 = blockIdx.x * 128, b = blockIdx.y;
    const int o = o0 + tid;
    const int pco = (o < 448) ? posk(o) : 0;
    const int rsub = lane >> 5;
    const int koff = (lane & 31) << 2;
    float v = 0.f;
    for (int n0 = 0; n0 < 400; n0 += 40) {
        #pragma unroll
        for (int g = 0; g < 10; ++g) {
            int r = w * 20 + g * 2;
            const float* src = y + ((long)(n0 + r + rsub) * 64 + b) * 512 + o0 + koff;
            async16(src, &buf[r][0]);
        }
        __syncthreads();
        #pragma unroll 8
        for (int r = 0; r < 40; ++r) {
            float cur = buf[r][tid];
            v += (cur - v) * 0.5f;
            bool sk = (v >= 1.0f);
            if (o < 448)
                s2[((long)(n0 + r) * 64 + b) * 448 + pco] = sk ? (unsigned short)0x3F80 : (unsigned short)0;
            if (sk) v = 0.f;
        }
        __syncthreads();
    }
}

// ---------------- MFMA GEMM 128x128 tile, 512 threads / 8 waves (2m x 4n) -------------------
// Per-wave 64x32 output (acc[4][2]). BK=64, double-buffered 64KB LDS, counted vmcnt(4)
// 2-phase pipeline. Panel-grouped 1-D dispatch: xcd=id&7 -> panel-sharers at ids p,p+8,..
// GMODE 0: panel = A m-block (nb = n-block, NB=1<<NBL) | 1: panel = B n-block |
//       2: cp batched: panel=(b,m-block), nb = n-block
template<int EPI, int GMODE, int NBL>
__global__ __launch_bounds__(512) void mfma_gemm(
    const unsigned short* __restrict__ A, int ldA, long sAb,
    const unsigned short* __restrict__ B, int ldB,
    int KT, int wrapK,
    void* __restrict__ Cv,
    const float* __restrict__ p0, const float* __restrict__ p1)
{
    __shared__ char LDS[2][32768];   // [buf][A 16KB | B 16KB]
    const int tid = threadIdx.x;
    const int lane = tid & 63, wid = tid >> 6;      // 8 waves
    const int wm = wid >> 2, wn = wid & 3;           // 2m x 4n
    int m0, n0, bz = 0;
    {
        int id = blockIdx.x;
        int xcd = id & 7, q = id >> 3;
        if (GMODE == 0) {
            int nb = q & ((1 << NBL) - 1);
            int rest = q >> NBL;
            m0 = (rest * 8 + xcd) << 7;
            n0 = nb << 7;
        } else if (GMODE == 1) {
            int mb = q & ((1 << NBL) - 1);
            int rest = q >> NBL;
            n0 = (rest * 8 + xcd) << 7;
            m0 = mb << 7;
        } else {
            int nb = q & 3;
            int rest = q >> 2;
            int p = rest * 8 + xcd;
            bz = p & 63;
            m0 = (p >> 6) << 7;
            n0 = nb << 7;
        }
    }
    const unsigned short* Ab = A + (long)bz * sAb;

    const int srow = lane >> 3;
    const int koff = (lane & 7) << 4;
    const int ssw  = (srow & 7) << 4;

    f32x4 acc[4][2];
    #pragma unroll
    for (int i = 0; i < 4; ++i)
        #pragma unroll
        for (int j = 0; j < 2; ++j)
            acc[i][j] = (f32x4){0.f, 0.f, 0.f, 0.f};

    auto stage = [&](char* dst, int kt){
        int k0 = kt << 6;
        int k0a = (wrapK && k0 >= wrapK) ? (k0 - wrapK) : k0;
        #pragma unroll
        for (int qq = 0; qq < 2; ++qq) {
            int i = (wid << 1) + qq;         // 0..15 (16 x 1KB segments each for A and B)
            int row = (i << 3) + srow;       // 0..127
            const char* gA = (const char*)(Ab + (long)(m0 + row) * ldA + k0a) + (koff ^ ssw);
            async16(gA, dst + (i << 10));
            const char* gB = (const char*)(B + (long)(n0 + row) * ldB + k0) + (koff ^ ssw);
            async16(gB, dst + 16384 + (i << 10));
        }
    };

    const int r16 = lane & 15;
    const int swl = (r16 & 7) << 4;

    stage(LDS[0], 0);   // prologue: 4 loads/wave in flight
    int cur = 0;
    for (int kt = 0; kt < KT; ++kt) {
        asm volatile("" ::: "memory");
        if (kt + 1 < KT) {
            stage(LDS[cur ^ 1], kt + 1);                       // +4 (8 outstanding)
            asm volatile("s_waitcnt vmcnt(4)" ::: "memory");   // cur-tile loads landed
        } else {
            asm volatile("s_waitcnt vmcnt(0)" ::: "memory");
        }
        __builtin_amdgcn_s_barrier();                          // everyone's landed
        asm volatile("" ::: "memory");
        __builtin_amdgcn_sched_barrier(0);
        const char* AsB = LDS[cur];
        const char* BsB = LDS[cur] + 16384;
        #pragma unroll
        for (int kk = 0; kk < 2; ++kk) {
            int kb = (kk << 6) + ((lane >> 4) << 4);
            s8v af[4], bv[2];
            #pragma unroll
            for (int f = 0; f < 4; ++f) {
                int rowA = (wm << 6) + (f << 4) + r16;
                af[f] = *reinterpret_cast<const s8v*>(AsB + (rowA << 7) + (kb ^ swl));
            }
            #pragma unroll
            for (int f = 0; f < 2; ++f) {
                int rowB = (wn << 5) + (f << 4) + r16;
                bv[f] = *reinterpret_cast<const s8v*>(BsB + (rowB << 7) + (kb ^ swl));
            }
            #pragma unroll
            for (int fi = 0; fi < 4; ++fi)
                #pragma unroll
                for (int fj = 0; fj < 2; ++fj)
                    acc[fi][fj] = __builtin_amdgcn_mfma_f32_16x16x32_bf16(af[fi], bv[fj], acc[fi][fj], 0, 0, 0);
        }
        asm volatile("" ::: "memory");
        __builtin_amdgcn_s_barrier();   // all waves done with LDS[cur] before restage
        cur ^= 1;
    }

    const int g4 = (lane >> 4) << 2;
    unsigned short* hC = (unsigned short*)Cv;
    float* fC = (float*)Cv;
    #pragma unroll
    for (int fi = 0; fi < 4; ++fi) {
        #pragma unroll
        for (int fj = 0; fj < 2; ++fj) {
            int col = n0 + (wn << 5) + (fj << 4) + r16;
            int row0 = m0 + (wm << 6) + (fi << 4) + g4;
            f32x4 a = acc[fi][fj];
            if (EPI == 0) {
                if (col < 448) {
                    float bias = p0[col];
                    int pc = posk(col);
                    #pragma unroll
                    for (int r = 0; r < 4; ++r)
                        hC[(long)(row0 + r) * 448 + pc] = f2bf(fmaxf(a[r] + bias, 0.f));
                }
            } else if (EPI == 1) {
                int bb = col >> 10, cc = col & 1023;
                int pc = posk(cc);
                if (row0 < 400) {
                    float4 rv = *reinterpret_cast<const float4*>(p1 + ((long)bb * 1024 + cc) * 400 + row0);
                    float ra[4] = {rv.x, rv.y, rv.z, rv.w};
                    #pragma unroll
                    for (int r = 0; r < 4; ++r) {
                        float t = a[r] + p0[row0 + r] + ra[r];
                        hC[(long)bb * 409600 + (long)(row0 + r) * 1024 + pc] = f2bf(t);
                    }
                }
            } else if (EPI == 2) {
                float sc = p0[col], sh = p1[col];
                #pragma unroll
                for (int r = 0; r < 4; ++r)
                    fC[(long)(row0 + r) * 512 + col] = a[r] * sc + sh;
            } else if (EPI == 3) {
                float sc = p0[col], sh = p1[col];
                int pc = posk(col);
                #pragma unroll
                for (int r = 0; r < 4; ++r) {
                    int row = row0 + r;
                    int nn = row >> 6, bbb = row & 63;
                    long ad = ((long)bbb * 400 + nn) * 1024 + pc;
                    hC[ad] = f2bf(bf2f(hC[ad]) + a[r] * sc + sh);
                }
            } else {
                float bias = p0[col];
                if (row0 < 400) {
                    #pragma unroll
                    for (int r = 0; r < 4; ++r)
                        hC[(long)bz * 204800 + (long)(row0 + r) * 512 + col] = f2bf(a[r] + bias);
                }
            }
        }
    }
}

// ---------------- rp GEMM + L2 normalize (xc is bf16 [b][n][o]) ----------------
__global__ __launch_bounds__(512) void rp_norm(const unsigned short* __restrict__ xc,
        const float* __restrict__ rpw, const float* __restrict__ rpb,
        float* __restrict__ out)
{
    __shared__ float wr[1600];
    __shared__ float red[8];
    int b = blockIdx.x, o = threadIdx.x;
    for (int i = o; i < 1600; i += 512) wr[i] = rpw[i];
    __syncthreads();
    const unsigned short* xb = xc + (long)b * 204800 + o;
    float a0 = rpb[0], a1 = rpb[1], a2 = rpb[2], a3 = rpb[3];
    #pragma unroll 4
    for (int n = 0; n < 400; ++n) {
        float xv = bf2f(xb[(long)n * 512]);
        a0 = fmaf(xv, wr[n], a0);
        a1 = fmaf(xv, wr[400 + n], a1);
        a2 = fmaf(xv, wr[800 + n], a2);
        a3 = fmaf(xv, wr[1200 + n], a3);
    }
    float sq = a0*a0 + a1*a1 + a2*a2 + a3*a3;
    #pragma unroll
    for (int off2 = 32; off2; off2 >>= 1) sq += __shfl_down(sq, off2);
    if ((o & 63) == 0) red[o >> 6] = sq;
    __syncthreads();
    if (o == 0) {
        float t = 0.f;
        #pragma unroll
        for (int i = 0; i < 8; ++i) t += red[i];
        red[0] = fmaxf(sqrtf(t), 1e-12f);
    }
    __syncthreads();
    float inv = 1.f / red[0];
    float4 ov = make_float4(a0*inv, a1*inv, a2*inv, a3*inv);
    *reinterpret_cast<float4*>(out + (long)b * 2048 + o * 4) = ov;
}

extern "C" void kernel_launch(void* const* d_in, const int* in_sizes, int n_in,
                              void* d_out, int out_size, void* d_ws, size_t ws_size,
                              hipStream_t stream) {
    const float* x    = (const float*)d_in[0];
    const float* ln_g = (const float*)d_in[1];
    const float* ln_b = (const float*)d_in[2];
    const float* w1   = (const float*)d_in[3];
    const float* b1   = (const float*)d_in[4];
    const float* w2   = (const float*)d_in[5];
    const float* b2   = (const float*)d_in[6];
    const float* c1w  = (const float*)d_in[7];
    const float* c1b  = (const float*)d_in[8];
    const float* bn1g = (const float*)d_in[9];
    const float* bn1b = (const float*)d_in[10];
    const float* bn1m = (const float*)d_in[11];
    const float* bn1v = (const float*)d_in[12];
    const float* c2w  = (const float*)d_in[13];
    const float* c2b  = (const float*)d_in[14];
    const float* bn2g = (const float*)d_in[15];
    const float* bn2b = (const float*)d_in[16];
    const float* bn2m = (const float*)d_in[17];
    const float* bn2v = (const float*)d_in[18];
    const float* cpw  = (const float*)d_in[19];
    const float* cpb  = (const float*)d_in[20];
    const float* rpw  = (const float*)d_in[21];
    const float* rpb  = (const float*)d_in[22];

    char* ws = (char*)d_ws;
    size_t off = 0;
    auto alloc = [&](size_t n){ size_t o = off; off += (n + 255) & ~(size_t)255; return o; };

    unsigned short* regA = (unsigned short*)(ws + alloc(58720256));
    unsigned short* regB = (unsigned short*)(ws + alloc(58720256));
    char* regC = ws + alloc(104857600);

    unsigned short* xln  = regA;
    unsigned short* x1bf = regA;
    unsigned short* h1   = regB;
    unsigned short* s    = regB;
    float* y  = (float*)regC;                                // 25600*512*4 = 52.4MB
    unsigned short* s2 = (unsigned short*)(regC + 52428800); // 25600*448*2 = 22.9MB
    unsigned short* xc = (unsigned short*)regC;              // 64*400*512*2 (after lif2 consumes y)

    unsigned short* w1p  = (unsigned short*)(ws + alloc(458752));
    unsigned short* w2p  = (unsigned short*)(ws + alloc(458752));
    unsigned short* w1c  = (unsigned short*)(ws + alloc(2097152));  // [512][2048] hi|lo
    unsigned short* w2c  = (unsigned short*)(ws + alloc(1835008));  // [1024][448]
    unsigned short* cpwp = (unsigned short*)(ws + alloc(1048576));
    float* b1p = (float*)(ws + alloc(2048));
    float* b2p = (float*)(ws + alloc(2048));
    float* sc1 = (float*)(ws + alloc(2048));
    float* sh1 = (float*)(ws + alloc(2048));
    float* sc2 = (float*)(ws + alloc(4096));
    float* sh2 = (float*)(ws + alloc(4096));

    prep_w<<<dim3(2, 512), 256, 0, stream>>>(w1, 400, 400, w1p, 448, 0);
    prep_w<<<dim3(2, 512), 256, 0, stream>>>(w2, 400, 400, w2p, 448, 0);
    prep_w<<<dim3(8, 512), 256, 0, stream>>>(c1w, 400, 1024, w1c, 2048, 1024);
    prep_w<<<dim3(2, 1024), 256, 0, stream>>>(c2w, 1024, 400, w2c, 448, 0);
    prep_w<<<dim3(4, 512), 256, 0, stream>>>(cpw, 512, 1024, cpwp, 1024, 0);
    prep_params<<<1, 1024, 0, stream>>>(b1, b2, c1b, bn1g, bn1b, bn1m, bn1v,
                                        c2b, bn2g, bn2b, bn2m, bn2v,
                                        b1p, b2p, sc1, sh1, sc2, sh2);

    // 1) LN(x) -> xln
    ln_fused<<<16384, 256, 0, stream>>>(x, ln_g, ln_b, xln);

    // 2) h1 = relu(xln @ w1p^T + b1)   [GMODE0: A-panel sharers at dispatch stride 8 -> same XCD]
    mfma_gemm<0,0,2><<<dim3(2048), 512, 0, stream>>>(xln, 448, 0, w1p, 448, 7, 0, h1, b1p, nullptr);

    // 3) x1bf[b][n][c] = (h1 @ w2^T)^T + b2 + x   [GMODE1: B-panel (h1) sharers stride 8]
    mfma_gemm<1,1,2><<<dim3(2048), 512, 0, stream>>>(w2p, 448, 0, h1, 448, 7, 0, x1bf, b2p, x);

    // 4) LIF1 (direct x scan): -> s
    lif1<<<dim3(8, 64), 128, 0, stream>>>(x, s);

    // 5) conv1+bn1 (hi/lo split, K=2048 wrap 1024)  [GMODE0]
    mfma_gemm<2,0,2><<<dim3(800), 512, 0, stream>>>(s, 1024, 0, w1c, 2048, 32, 1024, y, sc1, sh1);

    // 6) LIF2 (LDS-staged): y -> s2
    lif2<<<dim3(4, 64), 128, 0, stream>>>(y, s2);

    // 7) conv2+bn2 (K=448; RMW into x1bf)  [GMODE0]
    mfma_gemm<3,0,3><<<dim3(1600), 512, 0, stream>>>(s2, 448, 0, w2c, 448, 7, 0, x1bf, sc2, sh2);

    // 8) cp: xc[b][n][o] = x1bf[b] @ cpw^T + cpb (bf16 out)  [GMODE2]
    mfma_gemm<4,2,2><<<dim3(1024), 512, 0, stream>>>(x1bf, 1024, 409600, cpwp, 1024, 16, 0, xc, cpb, nullptr);

    // 9) rp + L2 normalize
    rp_norm<<<64, 512, 0, stream>>>(xc, rpw, rpb, (float*)d_out);
}